// Round 6
// baseline (987.764 us; speedup 1.0000x reference)
//
#include <hip/hip_runtime.h>
#include <hip/hip_bf16.h>
#include <hip/hip_fp16.h>
#include <stdint.h>

// AttnBlock B=8 C=512 H=W=64 N=4096, 32 groups. fp16 MFMA (16x16x32) everywhere.
// Layouts: Ht[b][n][c], Qt/Kt[b][n][c], V[b][c][m], S/P[n][m] (per batch),
// ATTt[b][n][c]. All GEMMs take A row-major [M][K] and Bt row-major [N][K]
// (K contiguous for both) -> ds_read_b128 fragments, m97-style mainloop.
// ws aliasing: S->Ht (dead after k_qkv), ATTt->Qt (per-batch slot dead after its
// k_qk). Total ws = 164 MB.

#define C_DIM 512
#define N_DIM 4096
#define CN (512 * 4096)
#define BATCH 8

typedef _Float16 h8 __attribute__((ext_vector_type(8)));
typedef _Float16 h4 __attribute__((ext_vector_type(4)));
typedef float f4 __attribute__((ext_vector_type(4)));

__device__ __forceinline__ void gload16(const void* g, void* l) {
  __builtin_amdgcn_global_load_lds((const __attribute__((address_space(1))) void*)g,
                                   (__attribute__((address_space(3))) void*)l, 16, 0, 0);
}

// ---- shared mainloop: C[128][128] += A[128xK] * Bt[128xK]^T, BK=32 ----
// lsA/lsB: 4096 halfs each (128 rows x 32). acc[i][j] = 16x16 frag.
__device__ __forceinline__ void gemm_core(const _Float16* __restrict__ At, int lda,
                                          const _Float16* __restrict__ Bt, int ldb,
                                          int ksteps, _Float16* lsA, _Float16* lsB,
                                          f4 acc[4][4]) {
  const int t = threadIdx.x, w = t >> 6, lane = t & 63;
  const int rr = lane >> 2, kof = (lane & 3) * 8;     // staging row/col within chunk
  const _Float16* gA0 = At + (size_t)((w * 2 + 0) * 16 + rr) * lda + kof;
  const _Float16* gA1 = At + (size_t)((w * 2 + 1) * 16 + rr) * lda + kof;
  const _Float16* gB0 = Bt + (size_t)((w * 2 + 0) * 16 + rr) * ldb + kof;
  const _Float16* gB1 = Bt + (size_t)((w * 2 + 1) * 16 + rr) * ldb + kof;
  _Float16* lA0 = lsA + (w * 2 + 0) * 512;   // wave-uniform LDS base; lane x 16B linear
  _Float16* lA1 = lsA + (w * 2 + 1) * 512;
  _Float16* lB0 = lsB + (w * 2 + 0) * 512;
  _Float16* lB1 = lsB + (w * 2 + 1) * 512;
  const int wm = w >> 1, wn = w & 1;
  const int fr = lane & 15, fk = (lane >> 4) * 8;     // fragment row / k-offset
  for (int ks = 0; ks < ksteps; ++ks) {
    gload16(gA0, lA0);
    gload16(gA1, lA1);
    gload16(gB0, lB0);
    gload16(gB1, lB1);
    __syncthreads();   // drains vmcnt -> LDS tiles ready
    h8 af[4], bf[4];
#pragma unroll
    for (int i = 0; i < 4; ++i)
      af[i] = *(const h8*)&lsA[(wm * 64 + i * 16 + fr) * 32 + fk];
#pragma unroll
    for (int j = 0; j < 4; ++j)
      bf[j] = *(const h8*)&lsB[(wn * 64 + j * 16 + fr) * 32 + fk];
#pragma unroll
    for (int i = 0; i < 4; ++i)
#pragma unroll
      for (int j = 0; j < 4; ++j)
        acc[i][j] = __builtin_amdgcn_mfma_f32_16x16x32_f16(af[i], bf[j], acc[i][j], 0, 0, 0);
    __syncthreads();   // protect LDS before next stage
    gA0 += 32; gA1 += 32; gB0 += 32; gB1 += 32;
  }
}

// ---- epilogues ----
// direct fp16 store D[row][col] via LDS bounce (lsOut >= 128*136 halfs).
__device__ __forceinline__ void epi_f16_direct(f4 acc[4][4], _Float16* lsOut,
                                               _Float16* out, int ldo,
                                               const float* bias_tile, float scale) {
  const int t = threadIdx.x, lane = t & 63, w = t >> 6, wm = w >> 1, wn = w & 1;
  const int cr = lane >> 4, cc = lane & 15;
#pragma unroll
  for (int i = 0; i < 4; ++i) {
    const int r0 = wm * 64 + i * 16 + cr * 4;
    float b0 = 0.f, b1 = 0.f, b2 = 0.f, b3 = 0.f;
    if (bias_tile) { b0 = bias_tile[r0]; b1 = bias_tile[r0 + 1];
                     b2 = bias_tile[r0 + 2]; b3 = bias_tile[r0 + 3]; }
#pragma unroll
    for (int j = 0; j < 4; ++j) {
      const int cl = wn * 64 + j * 16 + cc;
      lsOut[(r0 + 0) * 136 + cl] = (_Float16)(acc[i][j].x * scale + b0);
      lsOut[(r0 + 1) * 136 + cl] = (_Float16)(acc[i][j].y * scale + b1);
      lsOut[(r0 + 2) * 136 + cl] = (_Float16)(acc[i][j].z * scale + b2);
      lsOut[(r0 + 3) * 136 + cl] = (_Float16)(acc[i][j].w * scale + b3);
    }
  }
  __syncthreads();
  const int row = t >> 1, co = (t & 1) * 64;
#pragma unroll
  for (int s = 0; s < 8; ++s)
    *(uint4*)(out + (size_t)row * ldo + co + s * 8) =
        *(const uint4*)&lsOut[row * 136 + co + s * 8];
}

// transposed fp16 store: outT[col][row] (for Qt/Kt).
__device__ __forceinline__ void epi_f16_trans(f4 acc[4][4], _Float16* lsOut,
                                              _Float16* outT, int ldo,
                                              const float* bias_tile) {
  const int t = threadIdx.x, lane = t & 63, w = t >> 6, wm = w >> 1, wn = w & 1;
  const int cr = lane >> 4, cc = lane & 15;
#pragma unroll
  for (int i = 0; i < 4; ++i) {
    const int r0 = wm * 64 + i * 16 + cr * 4;
    const float b0 = bias_tile[r0], b1 = bias_tile[r0 + 1];
    const float b2 = bias_tile[r0 + 2], b3 = bias_tile[r0 + 3];
#pragma unroll
    for (int j = 0; j < 4; ++j) {
      const int cl = wn * 64 + j * 16 + cc;
      h4 v = {(_Float16)(acc[i][j].x + b0), (_Float16)(acc[i][j].y + b1),
              (_Float16)(acc[i][j].z + b2), (_Float16)(acc[i][j].w + b3)};
      *(h4*)&lsOut[cl * 136 + r0] = v;
    }
  }
  __syncthreads();
  const int row = t >> 1, co = (t & 1) * 64;   // row = local col (n)
#pragma unroll
  for (int s = 0; s < 8; ++s)
    *(uint4*)(outT + (size_t)row * ldo + co + s * 8) =
        *(const uint4*)&lsOut[row * 136 + co + s * 8];
}

// direct fp32 store, optional bias (per row) + residual (same layout as out).
__device__ __forceinline__ void epi_f32_direct(f4 acc[4][4], float* out, int ldo,
                                               const float* bias_tile,
                                               const float* resid) {
  const int t = threadIdx.x, lane = t & 63, w = t >> 6, wm = w >> 1, wn = w & 1;
  const int cr = lane >> 4, cc = lane & 15;
#pragma unroll
  for (int i = 0; i < 4; ++i) {
    const int r0 = wm * 64 + i * 16 + cr * 4;
#pragma unroll
    for (int r = 0; r < 4; ++r) {
      const int row = r0 + r;
      const float bv = bias_tile ? bias_tile[row] : 0.f;
#pragma unroll
      for (int j = 0; j < 4; ++j) {
        const int col = wn * 64 + j * 16 + cc;
        float v = acc[i][j][r] + bv;
        if (resid) v += resid[(size_t)row * ldo + col];
        out[(size_t)row * ldo + col] = v;
      }
    }
  }
}

// ---- kernels ----
__global__ __launch_bounds__(256) void k_wcvt(const float* __restrict__ w0,
                                              const float* __restrict__ w1,
                                              const float* __restrict__ w2,
                                              const float* __restrict__ w3,
                                              _Float16* __restrict__ out) {
  const int z = blockIdx.y;
  const float* src = z == 0 ? w0 : z == 1 ? w1 : z == 2 ? w2 : w3;
  _Float16* dst = out + (size_t)z * (C_DIM * C_DIM);
  const int idx = (blockIdx.x * 256 + threadIdx.x) * 4;
  f4 v = *(const f4*)(src + idx);
  h4 o = {(_Float16)v.x, (_Float16)v.y, (_Float16)v.z, (_Float16)v.w};
  *(h4*)(dst + idx) = o;
}

__global__ __launch_bounds__(256) void k_gnstats(const float* __restrict__ x,
                                                 float* __restrict__ stats) {
  const int bg = blockIdx.x;
  const f4* x4 = (const f4*)(x + (size_t)bg * (16 * N_DIM));
  const int t = threadIdx.x;
  float s = 0.f, ss = 0.f;
#pragma unroll 4
  for (int i = 0; i < 64; ++i) {
    f4 v = x4[t + i * 256];
    s += v.x + v.y + v.z + v.w;
    ss += v.x * v.x + v.y * v.y + v.z * v.z + v.w * v.w;
  }
  __shared__ float reds[4], redq[4];
  for (int off = 32; off; off >>= 1) {
    s += __shfl_down(s, off);
    ss += __shfl_down(ss, off);
  }
  if ((t & 63) == 0) { reds[t >> 6] = s; redq[t >> 6] = ss; }
  __syncthreads();
  if (t == 0) {
    s = reds[0] + reds[1] + reds[2] + reds[3];
    ss = redq[0] + redq[1] + redq[2] + redq[3];
    const float mean = s * (1.f / (16 * N_DIM));
    const float var = ss * (1.f / (16 * N_DIM)) - mean * mean;
    stats[bg * 2] = mean;
    stats[bg * 2 + 1] = rsqrtf(var + 1e-6f);
  }
}

// normalize + transpose: Ht[b][n][c] fp16
__global__ __launch_bounds__(256) void k_gnapply(const float* __restrict__ x,
                                                 const float* __restrict__ gw,
                                                 const float* __restrict__ gb,
                                                 const float* __restrict__ stats,
                                                 _Float16* __restrict__ Ht) {
  __shared__ _Float16 lsT[64 * 72];
  const int n0 = blockIdx.x * 64, c0 = blockIdx.y * 64, b = blockIdx.z;
  const int t = threadIdx.x, rc = t >> 2, qc = t & 3;
  const int c = c0 + rc, g = c >> 4;
  const float mean = stats[(b * 32 + g) * 2], rstd = stats[(b * 32 + g) * 2 + 1];
  const float sc = gw[c] * rstd, of = gb[c] - mean * sc;
  const float* xr = x + ((size_t)b * C_DIM + c) * N_DIM + n0;
#pragma unroll
  for (int q = 0; q < 4; ++q) {
    const int f4i = qc + q * 4;
    f4 v = *(const f4*)(xr + f4i * 4);
    const int nl = f4i * 4;
    lsT[(nl + 0) * 72 + rc] = (_Float16)(v.x * sc + of);
    lsT[(nl + 1) * 72 + rc] = (_Float16)(v.y * sc + of);
    lsT[(nl + 2) * 72 + rc] = (_Float16)(v.z * sc + of);
    lsT[(nl + 3) * 72 + rc] = (_Float16)(v.w * sc + of);
  }
  __syncthreads();
  const int j = t >> 2, ch = (t & 3) * 16;
  _Float16* dst = Ht + ((size_t)b * N_DIM + n0 + j) * C_DIM + c0 + ch;
  *(uint4*)dst = *(const uint4*)&lsT[j * 72 + ch];
  *(uint4*)(dst + 8) = *(const uint4*)&lsT[j * 72 + ch + 8];
}

// QKV: D[o][n] = W[o][c] * Ht[n][c]^T ; Q,K stored transposed [n][o], V direct [o][n]
__global__ __launch_bounds__(256) void k_qkv(const _Float16* __restrict__ Wh,
                                             const float* __restrict__ bq,
                                             const float* __restrict__ bk,
                                             const float* __restrict__ bv,
                                             const _Float16* __restrict__ Ht,
                                             _Float16* __restrict__ Qt,
                                             _Float16* __restrict__ Kt,
                                             _Float16* __restrict__ V) {
  __shared__ _Float16 smem[128 * 136];
  const int z = blockIdx.z, b = z / 3, which = z - b * 3;
  const _Float16* A = Wh + (size_t)which * (C_DIM * C_DIM);
  const float* bias = which == 0 ? bq : which == 1 ? bk : bv;
  const int n0 = blockIdx.x * 128, m0 = blockIdx.y * 128;
  f4 acc[4][4] = {};
  gemm_core(A + (size_t)m0 * C_DIM, C_DIM,
            Ht + (size_t)b * CN + (size_t)n0 * C_DIM, C_DIM, 16,
            smem, smem + 4096, acc);
  if (which == 2) {
    epi_f16_direct(acc, smem, V + (size_t)b * CN + (size_t)m0 * N_DIM + n0, N_DIM,
                   bias + m0, 1.f);
  } else {
    _Float16* outT = (which == 0 ? Qt : Kt) + (size_t)b * CN + (size_t)n0 * C_DIM + m0;
    epi_f16_trans(acc, smem, outT, C_DIM, bias + m0);
  }
}

// S[n][m] = scale * Qt[n][:] . Kt[m][:]
__global__ __launch_bounds__(256) void k_qk(const _Float16* __restrict__ Qt,
                                            const _Float16* __restrict__ Kt,
                                            _Float16* __restrict__ S) {
  __shared__ _Float16 smem[128 * 136];
  const int m0 = blockIdx.x * 128, n0 = blockIdx.y * 128;
  f4 acc[4][4] = {};
  gemm_core(Qt + (size_t)n0 * C_DIM, C_DIM, Kt + (size_t)m0 * C_DIM, C_DIM, 16,
            smem, smem + 4096, acc);
  epi_f16_direct(acc, smem, S + (size_t)n0 * N_DIM + m0, N_DIM, nullptr,
                 0.04419417382415922f);
}

__global__ __launch_bounds__(256) void k_softmax(_Float16* __restrict__ S) {
  _Float16* row = S + (size_t)blockIdx.x * N_DIM;
  const int t = threadIdx.x, lane = t & 63, w = t >> 6;
  _Float16 v[16];
  *(uint4*)&v[0] = *(const uint4*)(row + t * 16);
  *(uint4*)&v[8] = *(const uint4*)(row + t * 16 + 8);
  float f[16], mx = -1e30f;
#pragma unroll
  for (int u = 0; u < 16; ++u) { f[u] = (float)v[u]; mx = fmaxf(mx, f[u]); }
  __shared__ float red[8];
  for (int off = 32; off; off >>= 1) mx = fmaxf(mx, __shfl_down(mx, off));
  if (lane == 0) red[w] = mx;
  __syncthreads();
  mx = fmaxf(fmaxf(red[0], red[1]), fmaxf(red[2], red[3]));
  float sum = 0.f;
#pragma unroll
  for (int u = 0; u < 16; ++u) { f[u] = __expf(f[u] - mx); sum += f[u]; }
  for (int off = 32; off; off >>= 1) sum += __shfl_down(sum, off);
  if (lane == 0) red[4 + w] = sum;
  __syncthreads();
  const float inv = 1.f / (red[4] + red[5] + red[6] + red[7]);
#pragma unroll
  for (int u = 0; u < 16; ++u) v[u] = (_Float16)(f[u] * inv);
  *(uint4*)(row + t * 16) = *(const uint4*)&v[0];
  *(uint4*)(row + t * 16 + 8) = *(const uint4*)&v[8];
}

// Ot[n][c] partial = P[n][m] * V[c][m]^T over quarter K range (split-K=4)
__global__ __launch_bounds__(256) void k_pv(const _Float16* __restrict__ P,
                                            const _Float16* __restrict__ V,
                                            float* __restrict__ Pp) {
  __shared__ _Float16 smem[2 * 4096];
  const int c0 = blockIdx.x * 128, n0 = blockIdx.y * 128, kz = blockIdx.z;
  f4 acc[4][4] = {};
  gemm_core(P + (size_t)n0 * N_DIM + kz * 1024, N_DIM,
            V + (size_t)c0 * N_DIM + kz * 1024, N_DIM, 32,
            smem, smem + 4096, acc);
  epi_f32_direct(acc, Pp + (size_t)kz * CN + (size_t)n0 * C_DIM + c0, C_DIM,
                 nullptr, nullptr);
}

__global__ __launch_bounds__(256) void k_pvred(const float* __restrict__ Pp,
                                               _Float16* __restrict__ ATTt) {
  const int idx = (blockIdx.x * 256 + threadIdx.x) * 8;
  float a[8];
#pragma unroll
  for (int u = 0; u < 8; ++u) a[u] = 0.f;
#pragma unroll
  for (int kz = 0; kz < 4; ++kz) {
    f4 p0 = *(const f4*)(Pp + (size_t)kz * CN + idx);
    f4 p1 = *(const f4*)(Pp + (size_t)kz * CN + idx + 4);
    a[0] += p0.x; a[1] += p0.y; a[2] += p0.z; a[3] += p0.w;
    a[4] += p1.x; a[5] += p1.y; a[6] += p1.z; a[7] += p1.w;
  }
  h8 o = {(_Float16)a[0], (_Float16)a[1], (_Float16)a[2], (_Float16)a[3],
          (_Float16)a[4], (_Float16)a[5], (_Float16)a[6], (_Float16)a[7]};
  *(h8*)(ATTt + idx) = o;
}

// out[o][n] = x + Wp[o][c] * ATTt[n][c]^T + bias
__global__ __launch_bounds__(256) void k_proj(const _Float16* __restrict__ Whp,
                                              const float* __restrict__ bp,
                                              const _Float16* __restrict__ ATTt,
                                              const float* __restrict__ x,
                                              float* __restrict__ out) {
  __shared__ _Float16 smem[2 * 4096];
  const int b = blockIdx.z, n0 = blockIdx.x * 128, m0 = blockIdx.y * 128;
  f4 acc[4][4] = {};
  gemm_core(Whp + (size_t)m0 * C_DIM, C_DIM,
            ATTt + (size_t)b * CN + (size_t)n0 * C_DIM, C_DIM, 16,
            smem, smem + 4096, acc);
  const size_t off = (size_t)b * CN + (size_t)m0 * N_DIM + n0;
  epi_f32_direct(acc, out + off, N_DIM, bp + m0, x + off);
}

extern "C" void kernel_launch(void* const* d_in, const int* in_sizes, int n_in,
                              void* d_out, int out_size, void* d_ws, size_t ws_size,
                              hipStream_t stream) {
  const float* x = (const float*)d_in[0];
  const float* gn_w = (const float*)d_in[1];
  const float* gn_b = (const float*)d_in[2];
  const float* q_w = (const float*)d_in[3];
  const float* q_b = (const float*)d_in[4];
  const float* k_w = (const float*)d_in[5];
  const float* k_b = (const float*)d_in[6];
  const float* v_w = (const float*)d_in[7];
  const float* v_b = (const float*)d_in[8];
  const float* p_w = (const float*)d_in[9];
  const float* p_b = (const float*)d_in[10];
  float* out = (float*)d_out;

  const size_t MB = 1024ull * 1024ull;
  if (ws_size < 164ull * MB) return;  // fail loudly if scratch too small
  char* ws = (char*)d_ws;
  _Float16* Wh    = (_Float16*)(ws + 0);          // 4 x 512x512 fp16 (2MB)
  float*    stats = (float*)(ws + 2 * MB);        // 256 x {mean,rstd}
  _Float16* Ht    = (_Float16*)(ws + 4 * MB);     // [b][n][c] (32MB); S aliases after qkv
  _Float16* Qt    = (_Float16*)(ws + 36 * MB);    // [b][n][c]; ATTt aliases per-batch
  _Float16* Kt    = (_Float16*)(ws + 68 * MB);    // [b][n][c]
  _Float16* V     = (_Float16*)(ws + 100 * MB);   // [b][c][m]
  float*    Pp    = (float*)(ws + 132 * MB);      // 4 x [n][c] fp32 partials (32MB)
  _Float16* S     = Ht;                            // [n][m] one batch (32MB)
  _Float16* ATTt  = Qt;                            // [b][n][c]

  k_wcvt<<<dim3(256, 4), 256, 0, stream>>>(q_w, k_w, v_w, p_w, Wh);
  k_gnstats<<<dim3(256), 256, 0, stream>>>(x, stats);
  k_gnapply<<<dim3(64, 8, 8), 256, 0, stream>>>(x, gn_w, gn_b, stats, Ht);
  k_qkv<<<dim3(32, 4, 24), 256, 0, stream>>>(Wh, q_b, k_b, v_b, Ht, Qt, Kt, V);
  for (int b = 0; b < BATCH; ++b) {
    k_qk<<<dim3(32, 32), 256, 0, stream>>>(Qt + (size_t)b * CN, Kt + (size_t)b * CN, S);
    k_softmax<<<dim3(4096), 256, 0, stream>>>(S);
    k_pv<<<dim3(4, 32, 4), 256, 0, stream>>>(S, V + (size_t)b * CN, Pp);
    k_pvred<<<dim3(1024), 256, 0, stream>>>(Pp, ATTt + (size_t)b * CN);
  }
  k_proj<<<dim3(32, 4, 8), 256, 0, stream>>>(Wh + 3 * C_DIM * C_DIM, p_b, ATTt, x, out);
}

// Round 7
// 971.288 us; speedup vs baseline: 1.0170x; 1.0170x over previous
//
#include <hip/hip_runtime.h>
#include <hip/hip_bf16.h>
#include <hip/hip_fp16.h>
#include <stdint.h>

// AttnBlock B=8 C=512 H=W=64 N=4096, 32 groups. fp16 MFMA (16x16x32).
// Round 7: batch attention kernels across batch dim (G batches per launch,
// G adaptive to ws_size), drop split-K + Pp + pvred (pv accumulates full
// K=4096 in registers, writes ATTt fp16 directly).
// Layouts: Ht[b][n][c], Qt/Kt[b][n][c], V[b][c][m], S[g][n][m], ATTt[b][n][c].
// ws: Wh 2MB | stats 2MB | Qt 32 | Kt 32 | V 32 | ATTt 32 | S = G*32MB
//     (Ht aliases the start of the S region; dead after k_qkv).

#define C_DIM 512
#define N_DIM 4096
#define CN (512 * 4096)
#define NN ((size_t)4096 * 4096)
#define BATCH 8

typedef _Float16 h8 __attribute__((ext_vector_type(8)));
typedef _Float16 h4 __attribute__((ext_vector_type(4)));
typedef float f4 __attribute__((ext_vector_type(4)));

__device__ __forceinline__ void gload16(const void* g, void* l) {
  __builtin_amdgcn_global_load_lds((const __attribute__((address_space(1))) void*)g,
                                   (__attribute__((address_space(3))) void*)l, 16, 0, 0);
}

// ---- shared mainloop: C[128][128] += A[128xK] * Bt[128xK]^T, BK=32 ----
__device__ __forceinline__ void gemm_core(const _Float16* __restrict__ At, int lda,
                                          const _Float16* __restrict__ Bt, int ldb,
                                          int ksteps, _Float16* lsA, _Float16* lsB,
                                          f4 acc[4][4]) {
  const int t = threadIdx.x, w = t >> 6, lane = t & 63;
  const int rr = lane >> 2, kof = (lane & 3) * 8;     // staging row/col within chunk
  const _Float16* gA0 = At + (size_t)((w * 2 + 0) * 16 + rr) * lda + kof;
  const _Float16* gA1 = At + (size_t)((w * 2 + 1) * 16 + rr) * lda + kof;
  const _Float16* gB0 = Bt + (size_t)((w * 2 + 0) * 16 + rr) * ldb + kof;
  const _Float16* gB1 = Bt + (size_t)((w * 2 + 1) * 16 + rr) * ldb + kof;
  _Float16* lA0 = lsA + (w * 2 + 0) * 512;   // wave-uniform LDS base; lane x 16B linear
  _Float16* lA1 = lsA + (w * 2 + 1) * 512;
  _Float16* lB0 = lsB + (w * 2 + 0) * 512;
  _Float16* lB1 = lsB + (w * 2 + 1) * 512;
  const int wm = w >> 1, wn = w & 1;
  const int fr = lane & 15, fk = (lane >> 4) * 8;     // fragment row / k-offset
  for (int ks = 0; ks < ksteps; ++ks) {
    gload16(gA0, lA0);
    gload16(gA1, lA1);
    gload16(gB0, lB0);
    gload16(gB1, lB1);
    __syncthreads();   // drains vmcnt -> LDS tiles ready
    h8 af[4], bf[4];
#pragma unroll
    for (int i = 0; i < 4; ++i)
      af[i] = *(const h8*)&lsA[(wm * 64 + i * 16 + fr) * 32 + fk];
#pragma unroll
    for (int j = 0; j < 4; ++j)
      bf[j] = *(const h8*)&lsB[(wn * 64 + j * 16 + fr) * 32 + fk];
#pragma unroll
    for (int i = 0; i < 4; ++i)
#pragma unroll
      for (int j = 0; j < 4; ++j)
        acc[i][j] = __builtin_amdgcn_mfma_f32_16x16x32_f16(af[i], bf[j], acc[i][j], 0, 0, 0);
    __syncthreads();   // protect LDS before next stage
    gA0 += 32; gA1 += 32; gB0 += 32; gB1 += 32;
  }
}

// ---- epilogues ----
__device__ __forceinline__ void epi_f16_direct(f4 acc[4][4], _Float16* lsOut,
                                               _Float16* out, int ldo,
                                               const float* bias_tile, float scale) {
  const int t = threadIdx.x, lane = t & 63, w = t >> 6, wm = w >> 1, wn = w & 1;
  const int cr = lane >> 4, cc = lane & 15;
#pragma unroll
  for (int i = 0; i < 4; ++i) {
    const int r0 = wm * 64 + i * 16 + cr * 4;
    float b0 = 0.f, b1 = 0.f, b2 = 0.f, b3 = 0.f;
    if (bias_tile) { b0 = bias_tile[r0]; b1 = bias_tile[r0 + 1];
                     b2 = bias_tile[r0 + 2]; b3 = bias_tile[r0 + 3]; }
#pragma unroll
    for (int j = 0; j < 4; ++j) {
      const int cl = wn * 64 + j * 16 + cc;
      lsOut[(r0 + 0) * 136 + cl] = (_Float16)(acc[i][j].x * scale + b0);
      lsOut[(r0 + 1) * 136 + cl] = (_Float16)(acc[i][j].y * scale + b1);
      lsOut[(r0 + 2) * 136 + cl] = (_Float16)(acc[i][j].z * scale + b2);
      lsOut[(r0 + 3) * 136 + cl] = (_Float16)(acc[i][j].w * scale + b3);
    }
  }
  __syncthreads();
  const int row = t >> 1, co = (t & 1) * 64;
#pragma unroll
  for (int s = 0; s < 8; ++s)
    *(uint4*)(out + (size_t)row * ldo + co + s * 8) =
        *(const uint4*)&lsOut[row * 136 + co + s * 8];
}

__device__ __forceinline__ void epi_f16_trans(f4 acc[4][4], _Float16* lsOut,
                                              _Float16* outT, int ldo,
                                              const float* bias_tile) {
  const int t = threadIdx.x, lane = t & 63, w = t >> 6, wm = w >> 1, wn = w & 1;
  const int cr = lane >> 4, cc = lane & 15;
#pragma unroll
  for (int i = 0; i < 4; ++i) {
    const int r0 = wm * 64 + i * 16 + cr * 4;
    const float b0 = bias_tile[r0], b1 = bias_tile[r0 + 1];
    const float b2 = bias_tile[r0 + 2], b3 = bias_tile[r0 + 3];
#pragma unroll
    for (int j = 0; j < 4; ++j) {
      const int cl = wn * 64 + j * 16 + cc;
      h4 v = {(_Float16)(acc[i][j].x + b0), (_Float16)(acc[i][j].y + b1),
              (_Float16)(acc[i][j].z + b2), (_Float16)(acc[i][j].w + b3)};
      *(h4*)&lsOut[cl * 136 + r0] = v;
    }
  }
  __syncthreads();
  const int row = t >> 1, co = (t & 1) * 64;   // row = local col (n)
#pragma unroll
  for (int s = 0; s < 8; ++s)
    *(uint4*)(outT + (size_t)row * ldo + co + s * 8) =
        *(const uint4*)&lsOut[row * 136 + co + s * 8];
}

__device__ __forceinline__ void epi_f32_direct(f4 acc[4][4], float* out, int ldo,
                                               const float* bias_tile,
                                               const float* resid) {
  const int t = threadIdx.x, lane = t & 63, w = t >> 6, wm = w >> 1, wn = w & 1;
  const int cr = lane >> 4, cc = lane & 15;
#pragma unroll
  for (int i = 0; i < 4; ++i) {
    const int r0 = wm * 64 + i * 16 + cr * 4;
#pragma unroll
    for (int r = 0; r < 4; ++r) {
      const int row = r0 + r;
      const float bv = bias_tile ? bias_tile[row] : 0.f;
#pragma unroll
      for (int j = 0; j < 4; ++j) {
        const int col = wn * 64 + j * 16 + cc;
        float v = acc[i][j][r] + bv;
        if (resid) v += resid[(size_t)row * ldo + col];
        out[(size_t)row * ldo + col] = v;
      }
    }
  }
}

// ---- kernels ----
__global__ __launch_bounds__(256) void k_wcvt(const float* __restrict__ w0,
                                              const float* __restrict__ w1,
                                              const float* __restrict__ w2,
                                              const float* __restrict__ w3,
                                              _Float16* __restrict__ out) {
  const int z = blockIdx.y;
  const float* src = z == 0 ? w0 : z == 1 ? w1 : z == 2 ? w2 : w3;
  _Float16* dst = out + (size_t)z * (C_DIM * C_DIM);
  const int idx = (blockIdx.x * 256 + threadIdx.x) * 4;
  f4 v = *(const f4*)(src + idx);
  h4 o = {(_Float16)v.x, (_Float16)v.y, (_Float16)v.z, (_Float16)v.w};
  *(h4*)(dst + idx) = o;
}

__global__ __launch_bounds__(256) void k_gnstats(const float* __restrict__ x,
                                                 float* __restrict__ stats) {
  const int bg = blockIdx.x;
  const f4* x4 = (const f4*)(x + (size_t)bg * (16 * N_DIM));
  const int t = threadIdx.x;
  float s = 0.f, ss = 0.f;
#pragma unroll 4
  for (int i = 0; i < 64; ++i) {
    f4 v = x4[t + i * 256];
    s += v.x + v.y + v.z + v.w;
    ss += v.x * v.x + v.y * v.y + v.z * v.z + v.w * v.w;
  }
  __shared__ float reds[4], redq[4];
  for (int off = 32; off; off >>= 1) {
    s += __shfl_down(s, off);
    ss += __shfl_down(ss, off);
  }
  if ((t & 63) == 0) { reds[t >> 6] = s; redq[t >> 6] = ss; }
  __syncthreads();
  if (t == 0) {
    s = reds[0] + reds[1] + reds[2] + reds[3];
    ss = redq[0] + redq[1] + redq[2] + redq[3];
    const float mean = s * (1.f / (16 * N_DIM));
    const float var = ss * (1.f / (16 * N_DIM)) - mean * mean;
    stats[bg * 2] = mean;
    stats[bg * 2 + 1] = rsqrtf(var + 1e-6f);
  }
}

__global__ __launch_bounds__(256) void k_gnapply(const float* __restrict__ x,
                                                 const float* __restrict__ gw,
                                                 const float* __restrict__ gb,
                                                 const float* __restrict__ stats,
                                                 _Float16* __restrict__ Ht) {
  __shared__ _Float16 lsT[64 * 72];
  const int n0 = blockIdx.x * 64, c0 = blockIdx.y * 64, b = blockIdx.z;
  const int t = threadIdx.x, rc = t >> 2, qc = t & 3;
  const int c = c0 + rc, g = c >> 4;
  const float mean = stats[(b * 32 + g) * 2], rstd = stats[(b * 32 + g) * 2 + 1];
  const float sc = gw[c] * rstd, of = gb[c] - mean * sc;
  const float* xr = x + ((size_t)b * C_DIM + c) * N_DIM + n0;
#pragma unroll
  for (int q = 0; q < 4; ++q) {
    const int f4i = qc + q * 4;
    f4 v = *(const f4*)(xr + f4i * 4);
    const int nl = f4i * 4;
    lsT[(nl + 0) * 72 + rc] = (_Float16)(v.x * sc + of);
    lsT[(nl + 1) * 72 + rc] = (_Float16)(v.y * sc + of);
    lsT[(nl + 2) * 72 + rc] = (_Float16)(v.z * sc + of);
    lsT[(nl + 3) * 72 + rc] = (_Float16)(v.w * sc + of);
  }
  __syncthreads();
  const int j = t >> 2, ch = (t & 3) * 16;
  _Float16* dst = Ht + ((size_t)b * N_DIM + n0 + j) * C_DIM + c0 + ch;
  *(uint4*)dst = *(const uint4*)&lsT[j * 72 + ch];
  *(uint4*)(dst + 8) = *(const uint4*)&lsT[j * 72 + ch + 8];
}

// QKV: D[o][n] = W[o][c] * Ht[n][c]^T ; Q,K stored transposed [n][o], V direct [o][n]
__global__ __launch_bounds__(256) void k_qkv(const _Float16* __restrict__ Wh,
                                             const float* __restrict__ bq,
                                             const float* __restrict__ bk,
                                             const float* __restrict__ bv,
                                             const _Float16* __restrict__ Ht,
                                             _Float16* __restrict__ Qt,
                                             _Float16* __restrict__ Kt,
                                             _Float16* __restrict__ V) {
  __shared__ _Float16 smem[128 * 136];
  const int z = blockIdx.z, b = z / 3, which = z - b * 3;
  const _Float16* A = Wh + (size_t)which * (C_DIM * C_DIM);
  const float* bias = which == 0 ? bq : which == 1 ? bk : bv;
  const int n0 = blockIdx.x * 128, m0 = blockIdx.y * 128;
  f4 acc[4][4] = {};
  gemm_core(A + (size_t)m0 * C_DIM, C_DIM,
            Ht + (size_t)b * CN + (size_t)n0 * C_DIM, C_DIM, 16,
            smem, smem + 4096, acc);
  if (which == 2) {
    epi_f16_direct(acc, smem, V + (size_t)b * CN + (size_t)m0 * N_DIM + n0, N_DIM,
                   bias + m0, 1.f);
  } else {
    _Float16* outT = (which == 0 ? Qt : Kt) + (size_t)b * CN + (size_t)n0 * C_DIM + m0;
    epi_f16_trans(acc, smem, outT, C_DIM, bias + m0);
  }
}

// S[bz][n][m] = scale * Qt[n][:] . Kt[m][:]   (bz = batch within group)
__global__ __launch_bounds__(256) void k_qk(const _Float16* __restrict__ Qt,
                                            const _Float16* __restrict__ Kt,
                                            _Float16* __restrict__ S) {
  __shared__ _Float16 smem[128 * 136];
  const int m0 = blockIdx.x * 128, n0 = blockIdx.y * 128, bz = blockIdx.z;
  f4 acc[4][4] = {};
  gemm_core(Qt + (size_t)bz * CN + (size_t)n0 * C_DIM, C_DIM,
            Kt + (size_t)bz * CN + (size_t)m0 * C_DIM, C_DIM, 16,
            smem, smem + 4096, acc);
  epi_f16_direct(acc, smem, S + (size_t)bz * NN + (size_t)n0 * N_DIM + m0, N_DIM,
                 nullptr, 0.04419417382415922f);
}

__global__ __launch_bounds__(256) void k_softmax(_Float16* __restrict__ S) {
  _Float16* row = S + (size_t)blockIdx.y * NN + (size_t)blockIdx.x * N_DIM;
  const int t = threadIdx.x, lane = t & 63, w = t >> 6;
  _Float16 v[16];
  *(uint4*)&v[0] = *(const uint4*)(row + t * 16);
  *(uint4*)&v[8] = *(const uint4*)(row + t * 16 + 8);
  float f[16], mx = -1e30f;
#pragma unroll
  for (int u = 0; u < 16; ++u) { f[u] = (float)v[u]; mx = fmaxf(mx, f[u]); }
  __shared__ float red[8];
  for (int off = 32; off; off >>= 1) mx = fmaxf(mx, __shfl_down(mx, off));
  if (lane == 0) red[w] = mx;
  __syncthreads();
  mx = fmaxf(fmaxf(red[0], red[1]), fmaxf(red[2], red[3]));
  float sum = 0.f;
#pragma unroll
  for (int u = 0; u < 16; ++u) { f[u] = __expf(f[u] - mx); sum += f[u]; }
  for (int off = 32; off; off >>= 1) sum += __shfl_down(sum, off);
  if (lane == 0) red[4 + w] = sum;
  __syncthreads();
  const float inv = 1.f / (red[4] + red[5] + red[6] + red[7]);
#pragma unroll
  for (int u = 0; u < 16; ++u) v[u] = (_Float16)(f[u] * inv);
  *(uint4*)(row + t * 16) = *(const uint4*)&v[0];
  *(uint4*)(row + t * 16 + 8) = *(const uint4*)&v[8];
}

// ATTt[n][c] = P[n][m] * V[c][m]^T, full K=4096 (no split-K), fp16 out
__global__ __launch_bounds__(256) void k_pv(const _Float16* __restrict__ S,
                                            const _Float16* __restrict__ V,
                                            _Float16* __restrict__ ATTt) {
  __shared__ _Float16 smem[128 * 136];
  const int c0 = blockIdx.x * 128, n0 = blockIdx.y * 128, bz = blockIdx.z;
  f4 acc[4][4] = {};
  gemm_core(S + (size_t)bz * NN + (size_t)n0 * N_DIM, N_DIM,
            V + (size_t)bz * CN + (size_t)c0 * N_DIM, N_DIM, 128,
            smem, smem + 4096, acc);
  epi_f16_direct(acc, smem, ATTt + (size_t)bz * CN + (size_t)n0 * C_DIM + c0, C_DIM,
                 nullptr, 1.f);
}

// out[o][n] = x + Wp[o][c] * ATTt[n][c]^T + bias
__global__ __launch_bounds__(256) void k_proj(const _Float16* __restrict__ Whp,
                                              const float* __restrict__ bp,
                                              const _Float16* __restrict__ ATTt,
                                              const float* __restrict__ x,
                                              float* __restrict__ out) {
  __shared__ _Float16 smem[128 * 136];
  const int b = blockIdx.z, n0 = blockIdx.x * 128, m0 = blockIdx.y * 128;
  f4 acc[4][4] = {};
  gemm_core(Whp + (size_t)m0 * C_DIM, C_DIM,
            ATTt + (size_t)b * CN + (size_t)n0 * C_DIM, C_DIM, 16,
            smem, smem + 4096, acc);
  const size_t off = (size_t)b * CN + (size_t)m0 * N_DIM + n0;
  epi_f32_direct(acc, out + off, N_DIM, bp + m0, x + off);
}

extern "C" void kernel_launch(void* const* d_in, const int* in_sizes, int n_in,
                              void* d_out, int out_size, void* d_ws, size_t ws_size,
                              hipStream_t stream) {
  const float* x = (const float*)d_in[0];
  const float* gn_w = (const float*)d_in[1];
  const float* gn_b = (const float*)d_in[2];
  const float* q_b = (const float*)d_in[4];
  const float* k_b = (const float*)d_in[6];
  const float* v_b = (const float*)d_in[8];
  const float* p_b = (const float*)d_in[10];
  float* out = (float*)d_out;

  const size_t MB = 1024ull * 1024ull;
  if (ws_size < 164ull * MB) return;  // fail loudly if scratch too small
  // G = batches per attention launch, adaptive to available scratch.
  const int G = (ws_size >= 388ull * MB) ? 8
              : (ws_size >= 260ull * MB) ? 4
              : (ws_size >= 196ull * MB) ? 2 : 1;

  char* ws = (char*)d_ws;
  _Float16* Wh    = (_Float16*)(ws + 0);          // 4 x 512x512 fp16 (2MB)
  float*    stats = (float*)(ws + 2 * MB);        // 256 x {mean,rstd}
  _Float16* Qt    = (_Float16*)(ws + 4 * MB);     // [b][n][c] 32MB
  _Float16* Kt    = (_Float16*)(ws + 36 * MB);    // [b][n][c] 32MB
  _Float16* V     = (_Float16*)(ws + 68 * MB);    // [b][c][m] 32MB
  _Float16* ATTt  = (_Float16*)(ws + 100 * MB);   // [b][n][c] 32MB
  _Float16* Ht    = (_Float16*)(ws + 132 * MB);   // [b][n][c] 32MB, dead after qkv
  _Float16* S     = Ht;                           // [G][n][m] G*32MB (aliases Ht)

  k_wcvt<<<dim3(256, 4), 256, 0, stream>>>((const float*)d_in[3], (const float*)d_in[5],
                                           (const float*)d_in[7], (const float*)d_in[9], Wh);
  k_gnstats<<<dim3(256), 256, 0, stream>>>(x, stats);
  k_gnapply<<<dim3(64, 8, 8), 256, 0, stream>>>(x, gn_w, gn_b, stats, Ht);
  k_qkv<<<dim3(32, 4, 24), 256, 0, stream>>>(Wh, q_b, k_b, v_b, Ht, Qt, Kt, V);
  for (int g = 0; g < BATCH; g += G) {
    k_qk<<<dim3(32, 32, G), 256, 0, stream>>>(Qt + (size_t)g * CN, Kt + (size_t)g * CN, S);
    k_softmax<<<dim3(4096, G), 256, 0, stream>>>(S);
    k_pv<<<dim3(4, 32, G), 256, 0, stream>>>(S, V + (size_t)g * CN, ATTt + (size_t)g * CN);
  }
  k_proj<<<dim3(32, 4, 8), 256, 0, stream>>>(Wh + 3 * C_DIM * C_DIM, p_b, ATTt, x, out);
}